// Round 4
// baseline (93.227 us; speedup 1.0000x reference)
//
#include <hip/hip_runtime.h>
#include <hip/hip_bf16.h>

// softConLoss: loss = -mean_{i>=10} log_softmax_c( log(s_c(i)/py_c(i)) )[cls_i]
//   s_c(i) = sum_{j != i, cls_j == c} exp(feat_i . feat_j / 0.1)
// bf16 MFMA Gram tiles; columns permuted+padded so each 32-col tile is
// single-class; exp2 with pre-scaled operand; exact pad/diagonal correction.
// R4: 2-strip A-reuse in k_main (LDS-port was the bottleneck), ballot scatter,
// kernel fusion 6->5 launches.

constexpr int NROWS = 8192;
constexpr int DIM   = 128;
constexpr int NCLS  = 10;
constexpr int CS    = 16;       // column splits (grid.y of k_main)
constexpr int MMAX  = 8512;     // >= 8192 + 10*31, padded perm rows cap
constexpr int NCHUNK = 128;     // 64-row chunks for ballot scatter
constexpr float SCALEF = 14.4269504089f; // (1/TEMP) * log2(e)

typedef __attribute__((ext_vector_type(8)))  short  short8;
typedef __attribute__((ext_vector_type(16))) float  f32x16;

struct Meta { int cnt[NCLS]; int padc[NCLS]; int nTiles; };

// ---- workspace layout (bytes), ~9.7 MB ----
constexpr size_t OFF_FEATB   = 0;                                    // bf16 [NROWS][DIM], scaled
constexpr size_t OFF_FEATA   = OFF_FEATB + (size_t)NROWS * DIM * 2;  // bf16 [MMAX][DIM], permuted
constexpr size_t OFF_SLAB    = OFF_FEATA + (size_t)MMAX * DIM * 2;   // f32 [CS][NCLS][NROWS]
constexpr size_t OFF_DIAG    = OFF_SLAB + (size_t)CS * NCLS * NROWS * 4; // f32 [NROWS]
constexpr size_t OFF_CLS     = OFF_DIAG + (size_t)NROWS * 4;
constexpr size_t OFF_PERM    = OFF_CLS + (size_t)NROWS * 4;
constexpr size_t OFF_TILECLS = OFF_PERM + (size_t)MMAX * 4;
constexpr size_t OFF_HISTG   = OFF_TILECLS + 4 * 512;                // int [NCHUNK][NCLS]
constexpr size_t OFF_META    = OFF_HISTG + (size_t)NCHUNK * NCLS * 4;
constexpr size_t OFF_PART    = OFF_META + 128;                       // f32 [64]
constexpr size_t OFF_CNT     = OFF_PART + 256;                       // int

__device__ inline float exp2a(float x) {
#if __has_builtin(__builtin_amdgcn_exp2f)
  return __builtin_amdgcn_exp2f(x);
#else
  return exp2f(x);
#endif
}

// ---------- kernel 1: fused B-conv + diag + class ids + ballot chunk hists ----------
// 256 blocks x 256 thr = 65536 threads (one per float4 of feat).
__global__ void k_clsB(const float* __restrict__ label, const float* __restrict__ feat,
                       __hip_bfloat16* __restrict__ featB, float* __restrict__ diag,
                       int* __restrict__ cls, int* __restrict__ histg,
                       int* __restrict__ perm, int* __restrict__ counter) {
  const int gid = blockIdx.x * 256 + threadIdx.x;
  const int lane = threadIdx.x & 63;
  // --- featB = bf16(feat * SCALEF); diag[i] = exp2(sum bf16(a)*bf16(a*SCALEF)) ---
  {
    int e = gid * 4;
    float4 v = *(const float4*)(feat + e);
    __hip_bfloat16 b0 = __float2bfloat16(v.x * SCALEF);
    __hip_bfloat16 b1 = __float2bfloat16(v.y * SCALEF);
    __hip_bfloat16 b2 = __float2bfloat16(v.z * SCALEF);
    __hip_bfloat16 b3 = __float2bfloat16(v.w * SCALEF);
    featB[e + 0] = b0; featB[e + 1] = b1; featB[e + 2] = b2; featB[e + 3] = b3;
    float sd = __bfloat162float(__float2bfloat16(v.x)) * __bfloat162float(b0)
             + __bfloat162float(__float2bfloat16(v.y)) * __bfloat162float(b1)
             + __bfloat162float(__float2bfloat16(v.z)) * __bfloat162float(b2)
             + __bfloat162float(__float2bfloat16(v.w)) * __bfloat162float(b3);
#pragma unroll
    for (int st = 1; st < 32; st <<= 1) sd += __shfl_xor(sd, st, 64);
    if ((e & 127) == 0) diag[e >> 7] = exp2a(sd);
  }
  if (gid == 0) *counter = 0;           // reset every call (graph replays)
  if (gid < MMAX) perm[gid] = -1;       // pads stay -1
  if (gid < NROWS) {                    // 8192 % 64 == 0: waves fully active
    int c = 0;
#pragma unroll
    for (int j = 0; j < NCLS; ++j) if (label[gid * NCLS + j] > 0.5f) c = j;
    cls[gid] = c;
    const int chunk = gid >> 6;
#pragma unroll
    for (int cc = 0; cc < NCLS; ++cc) {
      unsigned long long m = __ballot(c == cc);
      if (lane == cc) histg[chunk * NCLS + cc] = __popcll(m);
    }
  }
}

// ---------- kernel 2: scan + meta + ballot scatter + tile classes (1 block, 1024 thr) ----------
__global__ void k_scatter(const int* __restrict__ cls, const int* __restrict__ histg,
                          int* __restrict__ perm, int* __restrict__ tileCls,
                          Meta* __restrict__ meta) {
  __shared__ int hist[NCHUNK][NCLS];
  __shared__ int gs[8][NCLS];
  __shared__ int ssb[NCLS + 1];
  __shared__ int snT;
  const int tid = threadIdx.x;
  for (int x = tid; x < NCHUNK * NCLS; x += 1024) ((int*)hist)[x] = histg[x];
  __syncthreads();
  const int g = tid / NCLS, c = tid % NCLS;   // 8 groups x 16 chunks
  if (tid < 8 * NCLS) {
    int s = 0;
#pragma unroll
    for (int j = 0; j < 16; ++j) s += hist[g * 16 + j][c];
    gs[g][c] = s;
  }
  __syncthreads();
  if (tid < NCLS) {
    int run = 0;
#pragma unroll
    for (int gg = 0; gg < 8; ++gg) { int v = gs[gg][tid]; gs[gg][tid] = run; run += v; }
    meta->cnt[tid] = run;
  }
  __syncthreads();
  if (tid == 0) {
    int s = 0;
    for (int cc = 0; cc < NCLS; ++cc) {
      ssb[cc] = s;
      int cnt = meta->cnt[cc];
      int seg = ((cnt + 31) >> 5) << 5;
      meta->padc[cc] = seg - cnt;
      s += seg;
    }
    ssb[NCLS] = s;
    meta->nTiles = s >> 5;
    snT = s >> 5;
  }
  __syncthreads();
  if (tid < 8 * NCLS) {
    int run = gs[g][c];
#pragma unroll
    for (int j = 0; j < 16; ++j) { int v = hist[g * 16 + j][c]; hist[g * 16 + j][c] = run; run += v; }
  }
  __syncthreads();
  // ballot scatter: 16 waves x 8 chunks x 64 rows, fully parallel ranking
  const int wv = tid >> 6, lane = tid & 63;
  const unsigned long long ltmask = (1ull << lane) - 1;
  for (int k = 0; k < 8; ++k) {
    const int chunk = wv * 8 + k;
    const int row = chunk * 64 + lane;
    const int myc = cls[row];
#pragma unroll
    for (int cc = 0; cc < NCLS; ++cc) {
      unsigned long long m = __ballot(myc == cc);
      if (myc == cc) {
        int rank = __popcll(m & ltmask);
        perm[ssb[cc] + hist[chunk][cc] + rank] = row;
      }
    }
  }
  for (int t = tid; t < snT; t += 1024) {
    int cc2 = 0;
    for (int c2 = 0; c2 < NCLS; ++c2) if (ssb[c2] <= t * 32) cc2 = c2;
    tileCls[t] = cc2;
  }
}

// ---------- kernel 3: featA = bf16(feat[perm]) (zeros for pads) ----------
__global__ void k_convA(const float* __restrict__ feat, const int* __restrict__ perm,
                        __hip_bfloat16* __restrict__ featA) {
  int e = (blockIdx.x * 256 + threadIdx.x) * 4;
  int p = e >> 7, k = e & 127;
  int src = perm[p];
  float4 v = make_float4(0.f, 0.f, 0.f, 0.f);
  if (src >= 0) v = *(const float4*)(feat + (size_t)src * DIM + k);
  featA[e + 0] = __float2bfloat16(v.x);
  featA[e + 1] = __float2bfloat16(v.y);
  featA[e + 2] = __float2bfloat16(v.z);
  featA[e + 3] = __float2bfloat16(v.w);
}

// ---------- kernel 4: main — Gram tiles -> exp2 -> per-class sums ----------
// 256 thr = 4 waves; each wave owns 64 output rows (2 strips of 32), so one
// A-fragment ds_read feeds 2 MFMAs (LDS port was the bottleneck at 1:1).
// Block covers 256 rows; grid (32, CS). Double-buffered LDS, reg prefetch.
__global__ __launch_bounds__(256, 2) void k_main(const __hip_bfloat16* __restrict__ featA,
                                                 const __hip_bfloat16* __restrict__ featB,
                                                 const int* __restrict__ tileCls,
                                                 const Meta* __restrict__ meta,
                                                 float* __restrict__ slab) {
  __shared__ __align__(16) char ldsA[2][8192];  // 2 x (32 rows x 256 B), XOR-swizzled
  const int tid  = threadIdx.x;
  const int lane = tid & 63, wid = tid >> 6;
  const int il   = lane & 31, hi = lane >> 5;
  const int rb   = blockIdx.x * 256 + wid * 64;
  const int i0   = rb + il, i1 = rb + 32 + il;
  const int split = blockIdx.y;

  const short8* fb0 = (const short8*)(featB + (size_t)i0 * DIM);
  const short8* fb1 = (const short8*)(featB + (size_t)i1 * DIM);
  short8 bfrag0[8], bfrag1[8];
#pragma unroll
  for (int kk = 0; kk < 8; ++kk) { bfrag0[kk] = fb0[kk * 2 + hi]; bfrag1[kk] = fb1[kk * 2 + hi]; }

  float acc0[NCLS], acc1[NCLS];
#pragma unroll
  for (int c = 0; c < NCLS; ++c) { acc0[c] = 0.f; acc1[c] = 0.f; }

  const int nT = meta->nTiles;

  // this thread's two 16B staging slots (swizzle: byte col ^= (row&15)<<4)
  const int r0 = tid >> 4, s0 = tid & 15;
  const int r1 = r0 + 16;
  const int off0 = r0 * 256 + ((s0 * 16) ^ ((r0 & 15) << 4));
  const int off1 = r1 * 256 + ((s0 * 16) ^ ((r1 & 15) << 4));

  {
    const short8* srcA = (const short8*)(featA + (size_t)split * 32 * DIM);
    *(short8*)(&ldsA[0][off0]) = srcA[r0 * 16 + s0];
    *(short8*)(&ldsA[0][off1]) = srcA[r1 * 16 + s0];
  }
  __syncthreads();

  int cur = 0;
  for (int t = split; t < nT; t += CS) {
    const int tn = t + CS;
    const bool pf = tn < nT;
    short8 v0, v1;
    if (pf) {  // issue next-tile loads early; latency hides under MFMA+exp
      const short8* srcA = (const short8*)(featA + (size_t)tn * 32 * DIM);
      v0 = srcA[r0 * 16 + s0];
      v1 = srcA[r1 * 16 + s0];
    }

    f32x16 D0, D1;
#pragma unroll
    for (int r = 0; r < 16; ++r) { D0[r] = 0.f; D1[r] = 0.f; }
#pragma unroll
    for (int kk = 0; kk < 8; ++kk) {
      int off = il * 256 + (((kk * 32) + hi * 16) ^ ((il & 15) << 4));
      short8 a = *(const short8*)(&ldsA[cur][off]);   // shared A fragment
      D0 = __builtin_amdgcn_mfma_f32_32x32x16_bf16(a, bfrag0[kk], D0, 0, 0, 0);
      D1 = __builtin_amdgcn_mfma_f32_32x32x16_bf16(a, bfrag1[kk], D1, 0, 0, 0);
    }

    // exp2 + pairwise tree sums
    float e0[8], e1[8];
#pragma unroll
    for (int r = 0; r < 8; ++r) {
      e0[r] = exp2a(D0[2 * r]) + exp2a(D0[2 * r + 1]);
      e1[r] = exp2a(D1[2 * r]) + exp2a(D1[2 * r + 1]);
    }
    float ts0 = ((e0[0] + e0[1]) + (e0[2] + e0[3])) + ((e0[4] + e0[5]) + (e0[6] + e0[7]));
    float ts1 = ((e1[0] + e1[1]) + (e1[2] + e1[3])) + ((e1[4] + e1[5]) + (e1[6] + e1[7]));

    const int ct = tileCls[t];  // wave-uniform switch keeps acc in regs
    switch (ct) {
      case 0: acc0[0] += ts0; acc1[0] += ts1; break;
      case 1: acc0[1] += ts0; acc1[1] += ts1; break;
      case 2: acc0[2] += ts0; acc1[2] += ts1; break;
      case 3: acc0[3] += ts0; acc1[3] += ts1; break;
      case 4: acc0[4] += ts0; acc1[4] += ts1; break;
      case 5: acc0[5] += ts0; acc1[5] += ts1; break;
      case 6: acc0[6] += ts0; acc1[6] += ts1; break;
      case 7: acc0[7] += ts0; acc1[7] += ts1; break;
      case 8: acc0[8] += ts0; acc1[8] += ts1; break;
      default: acc0[9] += ts0; acc1[9] += ts1; break;
    }

    if (pf) {  // write into the OTHER buffer: safe while others still compute on cur
      *(short8*)(&ldsA[cur ^ 1][off0]) = v0;
      *(short8*)(&ldsA[cur ^ 1][off1]) = v1;
    }
    __syncthreads();
    cur ^= 1;
  }

  // combine the two j-half lanes (il and il+32 hold different j's of same column)
#pragma unroll
  for (int c = 0; c < NCLS; ++c) {
    acc0[c] += __shfl_xor(acc0[c], 32, 64);
    acc1[c] += __shfl_xor(acc1[c], 32, 64);
  }
  if (lane < 32) {  // slab[split][c][i]: coalesced across il
#pragma unroll
    for (int c = 0; c < NCLS; ++c) {
      slab[((size_t)split * NCLS + c) * NROWS + i0] = acc0[c];
      slab[((size_t)split * NCLS + c) * NROWS + i1] = acc1[c];
    }
  }
}

// ---------- kernel 5: slab reduce + per-row loss + last-block final reduce ----------
__global__ void k_fin(const float* __restrict__ slab, const float* __restrict__ diag,
                      const int* __restrict__ cls, const Meta* __restrict__ meta,
                      float* __restrict__ partials, int* __restrict__ counter,
                      float* __restrict__ out) {
  __shared__ float red[128];
  const int tid = threadIdx.x;
  const int i = blockIdx.x * 128 + tid;   // 64 blocks x 128 thr
  const int ci = cls[i];
  float s[NCLS];
#pragma unroll
  for (int c = 0; c < NCLS; ++c) s[c] = 0.f;
#pragma unroll
  for (int sp = 0; sp < CS; ++sp) {
#pragma unroll
    for (int c = 0; c < NCLS; ++c) s[c] += slab[((size_t)sp * NCLS + c) * NROWS + i];
  }
  const float self = diag[i];
  float L[NCLS];
  float mx = -1e30f;
#pragma unroll
  for (int c = 0; c < NCLS; ++c) {
    float sc = s[c] - (float)meta->padc[c] - ((c == ci) ? self : 0.f);
    float py = (float)meta->cnt[c] - ((c == ci) ? 1.f : 0.f);
    L[c] = __logf(sc) - __logf(py);
    mx = fmaxf(mx, L[c]);
  }
  float sum = 0.f, Lt = 0.f;
#pragma unroll
  for (int c = 0; c < NCLS; ++c) {
    sum += __expf(L[c] - mx);
    Lt += (c == ci) ? L[c] : 0.f;
  }
  const float lse = mx + __logf(sum);
  red[tid] = (i >= NCLS) ? (lse - Lt) : 0.f;
  __syncthreads();
  for (int st = 64; st > 0; st >>= 1) {
    if (tid < st) red[tid] += red[tid + st];
    __syncthreads();
  }
  if (tid == 0) {
    partials[blockIdx.x] = red[0];
    __threadfence();
    int old = atomicAdd(counter, 1);
    if (old == (int)gridDim.x - 1) {      // last block: deterministic fixed-order sum
      __threadfence();
      float t = 0.f;
      for (int b = 0; b < (int)gridDim.x; ++b) t += partials[b];
      out[0] = t / (float)(NROWS - NCLS);
    }
  }
}

extern "C" void kernel_launch(void* const* d_in, const int* in_sizes, int n_in,
                              void* d_out, int out_size, void* d_ws, size_t ws_size,
                              hipStream_t stream) {
  const float* label = (const float*)d_in[0];
  const float* feat  = (const float*)d_in[1];
  char* w = (char*)d_ws;
  __hip_bfloat16* featB = (__hip_bfloat16*)(w + OFF_FEATB);
  __hip_bfloat16* featA = (__hip_bfloat16*)(w + OFF_FEATA);
  float* slab    = (float*)(w + OFF_SLAB);
  float* diag    = (float*)(w + OFF_DIAG);
  int*   cls     = (int*)(w + OFF_CLS);
  int*   perm    = (int*)(w + OFF_PERM);
  int*   tileCls = (int*)(w + OFF_TILECLS);
  int*   histg   = (int*)(w + OFF_HISTG);
  Meta*  meta    = (Meta*)(w + OFF_META);
  float* part    = (float*)(w + OFF_PART);
  int*   counter = (int*)(w + OFF_CNT);

  k_clsB<<<NROWS * DIM / 4 / 256, 256, 0, stream>>>(label, feat, featB, diag, cls, histg, perm, counter);
  k_scatter<<<1, 1024, 0, stream>>>(cls, histg, perm, tileCls, meta);
  k_convA<<<MMAX * DIM / 4 / 256, 256, 0, stream>>>(feat, perm, featA);
  k_main<<<dim3(32, CS), 256, 0, stream>>>(featA, featB, tileCls, meta, slab);
  k_fin<<<NROWS / 128, 128, 0, stream>>>(slab, diag, cls, meta, part, counter, (float*)d_out);
}

// Round 5
// 53.588 us; speedup vs baseline: 1.7397x; 1.7397x over previous
//
#include <hip/hip_runtime.h>
#include <hip/hip_bf16.h>

// softConLoss: loss = -mean_{i>=10} log_softmax_c( log(s_c(i)/py_c(i)) )[cls_i]
//   s_c(i) = sum_{j != i, cls_j == c} exp(feat_i . feat_j / 0.1)
// bf16 MFMA Gram tiles; columns permuted+padded so each 32-col tile is
// single-class; exp2 with pre-scaled operand; exact pad/diagonal correction.
// R5: restore wide k_sumslab (R4's k_fin fusion was latency-bound, 48us).

constexpr int NROWS = 8192;
constexpr int DIM   = 128;
constexpr int NCLS  = 10;
constexpr int CS    = 16;       // column splits (grid.y of k_main)
constexpr int MMAX  = 8512;     // >= 8192 + 10*31, padded perm rows cap
constexpr int NCHUNK = 128;     // 64-row chunks for ballot scatter
constexpr float SCALEF = 14.4269504089f; // (1/TEMP) * log2(e)

typedef __attribute__((ext_vector_type(8)))  short  short8;
typedef __attribute__((ext_vector_type(16))) float  f32x16;

struct Meta { int cnt[NCLS]; int padc[NCLS]; int nTiles; };

// ---- workspace layout (bytes), ~10 MB ----
constexpr size_t OFF_FEATB   = 0;                                    // bf16 [NROWS][DIM], scaled
constexpr size_t OFF_FEATA   = OFF_FEATB + (size_t)NROWS * DIM * 2;  // bf16 [MMAX][DIM], permuted
constexpr size_t OFF_SLAB    = OFF_FEATA + (size_t)MMAX * DIM * 2;   // f32 [CS][NCLS][NROWS]
constexpr size_t OFF_ROWSUM  = OFF_SLAB + (size_t)CS * NCLS * NROWS * 4; // f32 [NCLS][NROWS]
constexpr size_t OFF_DIAG    = OFF_ROWSUM + (size_t)NCLS * NROWS * 4;    // f32 [NROWS]
constexpr size_t OFF_CLS     = OFF_DIAG + (size_t)NROWS * 4;
constexpr size_t OFF_PERM    = OFF_CLS + (size_t)NROWS * 4;
constexpr size_t OFF_TILECLS = OFF_PERM + (size_t)MMAX * 4;
constexpr size_t OFF_HISTG   = OFF_TILECLS + 4 * 512;                // int [NCHUNK][NCLS]
constexpr size_t OFF_META    = OFF_HISTG + (size_t)NCHUNK * NCLS * 4;
constexpr size_t OFF_PART    = OFF_META + 128;                       // f32 [64]
constexpr size_t OFF_CNT     = OFF_PART + 256;                       // int

__device__ inline float exp2a(float x) {
#if __has_builtin(__builtin_amdgcn_exp2f)
  return __builtin_amdgcn_exp2f(x);
#else
  return exp2f(x);
#endif
}

// ---------- kernel 1: fused B-conv + diag + class ids + ballot chunk hists ----------
// 256 blocks x 256 thr = 65536 threads (one per float4 of feat).
__global__ void k_clsB(const float* __restrict__ label, const float* __restrict__ feat,
                       __hip_bfloat16* __restrict__ featB, float* __restrict__ diag,
                       int* __restrict__ cls, int* __restrict__ histg,
                       int* __restrict__ perm, int* __restrict__ counter) {
  const int gid = blockIdx.x * 256 + threadIdx.x;
  const int lane = threadIdx.x & 63;
  // --- featB = bf16(feat * SCALEF); diag[i] = exp2(sum bf16(a)*bf16(a*SCALEF)) ---
  {
    int e = gid * 4;
    float4 v = *(const float4*)(feat + e);
    __hip_bfloat16 b0 = __float2bfloat16(v.x * SCALEF);
    __hip_bfloat16 b1 = __float2bfloat16(v.y * SCALEF);
    __hip_bfloat16 b2 = __float2bfloat16(v.z * SCALEF);
    __hip_bfloat16 b3 = __float2bfloat16(v.w * SCALEF);
    featB[e + 0] = b0; featB[e + 1] = b1; featB[e + 2] = b2; featB[e + 3] = b3;
    float sd = __bfloat162float(__float2bfloat16(v.x)) * __bfloat162float(b0)
             + __bfloat162float(__float2bfloat16(v.y)) * __bfloat162float(b1)
             + __bfloat162float(__float2bfloat16(v.z)) * __bfloat162float(b2)
             + __bfloat162float(__float2bfloat16(v.w)) * __bfloat162float(b3);
#pragma unroll
    for (int st = 1; st < 32; st <<= 1) sd += __shfl_xor(sd, st, 64);
    if ((e & 127) == 0) diag[e >> 7] = exp2a(sd);
  }
  if (gid == 0) *counter = 0;           // reset every call (graph replays)
  if (gid < MMAX) perm[gid] = -1;       // pads stay -1
  if (gid < NROWS) {                    // 8192 % 64 == 0: waves fully active
    int c = 0;
#pragma unroll
    for (int j = 0; j < NCLS; ++j) if (label[gid * NCLS + j] > 0.5f) c = j;
    cls[gid] = c;
    const int chunk = gid >> 6;
#pragma unroll
    for (int cc = 0; cc < NCLS; ++cc) {
      unsigned long long m = __ballot(c == cc);
      if (lane == cc) histg[chunk * NCLS + cc] = __popcll(m);
    }
  }
}

// ---------- kernel 2: scan + meta + ballot scatter + tile classes (1 block, 1024 thr) ----------
__global__ void k_scatter(const int* __restrict__ cls, const int* __restrict__ histg,
                          int* __restrict__ perm, int* __restrict__ tileCls,
                          Meta* __restrict__ meta) {
  __shared__ int hist[NCHUNK][NCLS];
  __shared__ int gs[8][NCLS];
  __shared__ int ssb[NCLS + 1];
  __shared__ int snT;
  const int tid = threadIdx.x;
  for (int x = tid; x < NCHUNK * NCLS; x += 1024) ((int*)hist)[x] = histg[x];
  __syncthreads();
  const int g = tid / NCLS, c = tid % NCLS;   // 8 groups x 16 chunks
  if (tid < 8 * NCLS) {
    int s = 0;
#pragma unroll
    for (int j = 0; j < 16; ++j) s += hist[g * 16 + j][c];
    gs[g][c] = s;
  }
  __syncthreads();
  if (tid < NCLS) {
    int run = 0;
#pragma unroll
    for (int gg = 0; gg < 8; ++gg) { int v = gs[gg][tid]; gs[gg][tid] = run; run += v; }
    meta->cnt[tid] = run;
  }
  __syncthreads();
  if (tid == 0) {
    int s = 0;
    for (int cc = 0; cc < NCLS; ++cc) {
      ssb[cc] = s;
      int cnt = meta->cnt[cc];
      int seg = ((cnt + 31) >> 5) << 5;
      meta->padc[cc] = seg - cnt;
      s += seg;
    }
    ssb[NCLS] = s;
    meta->nTiles = s >> 5;
    snT = s >> 5;
  }
  __syncthreads();
  if (tid < 8 * NCLS) {
    int run = gs[g][c];
#pragma unroll
    for (int j = 0; j < 16; ++j) { int v = hist[g * 16 + j][c]; hist[g * 16 + j][c] = run; run += v; }
  }
  __syncthreads();
  // ballot scatter: 16 waves x 8 chunks x 64 rows, fully parallel ranking
  const int wv = tid >> 6, lane = tid & 63;
  const unsigned long long ltmask = (1ull << lane) - 1;
  for (int k = 0; k < 8; ++k) {
    const int chunk = wv * 8 + k;
    const int row = chunk * 64 + lane;
    const int myc = cls[row];
#pragma unroll
    for (int cc = 0; cc < NCLS; ++cc) {
      unsigned long long m = __ballot(myc == cc);
      if (myc == cc) {
        int rank = __popcll(m & ltmask);
        perm[ssb[cc] + hist[chunk][cc] + rank] = row;
      }
    }
  }
  for (int t = tid; t < snT; t += 1024) {
    int cc2 = 0;
    for (int c2 = 0; c2 < NCLS; ++c2) if (ssb[c2] <= t * 32) cc2 = c2;
    tileCls[t] = cc2;
  }
}

// ---------- kernel 3: featA = bf16(feat[perm]) (zeros for pads) ----------
__global__ void k_convA(const float* __restrict__ feat, const int* __restrict__ perm,
                        __hip_bfloat16* __restrict__ featA) {
  int e = (blockIdx.x * 256 + threadIdx.x) * 4;
  int p = e >> 7, k = e & 127;
  int src = perm[p];
  float4 v = make_float4(0.f, 0.f, 0.f, 0.f);
  if (src >= 0) v = *(const float4*)(feat + (size_t)src * DIM + k);
  featA[e + 0] = __float2bfloat16(v.x);
  featA[e + 1] = __float2bfloat16(v.y);
  featA[e + 2] = __float2bfloat16(v.z);
  featA[e + 3] = __float2bfloat16(v.w);
}

// ---------- kernel 4: main — Gram tiles -> exp2 -> per-class sums ----------
// 256 thr = 4 waves; each wave owns 64 output rows (2 strips of 32), so one
// A-fragment ds_read feeds 2 MFMAs (LDS port was the bottleneck at 1:1).
// Block covers 256 rows; grid (32, CS). Double-buffered LDS, reg prefetch.
__global__ __launch_bounds__(256, 2) void k_main(const __hip_bfloat16* __restrict__ featA,
                                                 const __hip_bfloat16* __restrict__ featB,
                                                 const int* __restrict__ tileCls,
                                                 const Meta* __restrict__ meta,
                                                 float* __restrict__ slab) {
  __shared__ __align__(16) char ldsA[2][8192];  // 2 x (32 rows x 256 B), XOR-swizzled
  const int tid  = threadIdx.x;
  const int lane = tid & 63, wid = tid >> 6;
  const int il   = lane & 31, hi = lane >> 5;
  const int rb   = blockIdx.x * 256 + wid * 64;
  const int i0   = rb + il, i1 = rb + 32 + il;
  const int split = blockIdx.y;

  const short8* fb0 = (const short8*)(featB + (size_t)i0 * DIM);
  const short8* fb1 = (const short8*)(featB + (size_t)i1 * DIM);
  short8 bfrag0[8], bfrag1[8];
#pragma unroll
  for (int kk = 0; kk < 8; ++kk) { bfrag0[kk] = fb0[kk * 2 + hi]; bfrag1[kk] = fb1[kk * 2 + hi]; }

  float acc0[NCLS], acc1[NCLS];
#pragma unroll
  for (int c = 0; c < NCLS; ++c) { acc0[c] = 0.f; acc1[c] = 0.f; }

  const int nT = meta->nTiles;

  // this thread's two 16B staging slots (swizzle: byte col ^= (row&15)<<4)
  const int r0 = tid >> 4, s0 = tid & 15;
  const int r1 = r0 + 16;
  const int off0 = r0 * 256 + ((s0 * 16) ^ ((r0 & 15) << 4));
  const int off1 = r1 * 256 + ((s0 * 16) ^ ((r1 & 15) << 4));

  {
    const short8* srcA = (const short8*)(featA + (size_t)split * 32 * DIM);
    *(short8*)(&ldsA[0][off0]) = srcA[r0 * 16 + s0];
    *(short8*)(&ldsA[0][off1]) = srcA[r1 * 16 + s0];
  }
  __syncthreads();

  int cur = 0;
  for (int t = split; t < nT; t += CS) {
    const int tn = t + CS;
    const bool pf = tn < nT;
    short8 v0, v1;
    if (pf) {  // issue next-tile loads early; latency hides under MFMA+exp
      const short8* srcA = (const short8*)(featA + (size_t)tn * 32 * DIM);
      v0 = srcA[r0 * 16 + s0];
      v1 = srcA[r1 * 16 + s0];
    }

    f32x16 D0, D1;
#pragma unroll
    for (int r = 0; r < 16; ++r) { D0[r] = 0.f; D1[r] = 0.f; }
#pragma unroll
    for (int kk = 0; kk < 8; ++kk) {
      int off = il * 256 + (((kk * 32) + hi * 16) ^ ((il & 15) << 4));
      short8 a = *(const short8*)(&ldsA[cur][off]);   // shared A fragment
      D0 = __builtin_amdgcn_mfma_f32_32x32x16_bf16(a, bfrag0[kk], D0, 0, 0, 0);
      D1 = __builtin_amdgcn_mfma_f32_32x32x16_bf16(a, bfrag1[kk], D1, 0, 0, 0);
    }

    // exp2 + pairwise tree sums
    float e0[8], e1[8];
#pragma unroll
    for (int r = 0; r < 8; ++r) {
      e0[r] = exp2a(D0[2 * r]) + exp2a(D0[2 * r + 1]);
      e1[r] = exp2a(D1[2 * r]) + exp2a(D1[2 * r + 1]);
    }
    float ts0 = ((e0[0] + e0[1]) + (e0[2] + e0[3])) + ((e0[4] + e0[5]) + (e0[6] + e0[7]));
    float ts1 = ((e1[0] + e1[1]) + (e1[2] + e1[3])) + ((e1[4] + e1[5]) + (e1[6] + e1[7]));

    const int ct = tileCls[t];  // wave-uniform switch keeps acc in regs
    switch (ct) {
      case 0: acc0[0] += ts0; acc1[0] += ts1; break;
      case 1: acc0[1] += ts0; acc1[1] += ts1; break;
      case 2: acc0[2] += ts0; acc1[2] += ts1; break;
      case 3: acc0[3] += ts0; acc1[3] += ts1; break;
      case 4: acc0[4] += ts0; acc1[4] += ts1; break;
      case 5: acc0[5] += ts0; acc1[5] += ts1; break;
      case 6: acc0[6] += ts0; acc1[6] += ts1; break;
      case 7: acc0[7] += ts0; acc1[7] += ts1; break;
      case 8: acc0[8] += ts0; acc1[8] += ts1; break;
      default: acc0[9] += ts0; acc1[9] += ts1; break;
    }

    if (pf) {  // write into the OTHER buffer: safe while others still compute on cur
      *(short8*)(&ldsA[cur ^ 1][off0]) = v0;
      *(short8*)(&ldsA[cur ^ 1][off1]) = v1;
    }
    __syncthreads();
    cur ^= 1;
  }

  // combine the two j-half lanes (il and il+32 hold different j's of same column)
#pragma unroll
  for (int c = 0; c < NCLS; ++c) {
    acc0[c] += __shfl_xor(acc0[c], 32, 64);
    acc1[c] += __shfl_xor(acc1[c], 32, 64);
  }
  if (lane < 32) {  // slab[split][c][i]: coalesced across il
#pragma unroll
    for (int c = 0; c < NCLS; ++c) {
      slab[((size_t)split * NCLS + c) * NROWS + i0] = acc0[c];
      slab[((size_t)split * NCLS + c) * NROWS + i1] = acc1[c];
    }
  }
}

// ---------- kernel 5: reduce slab over splits (coalesced, wide grid) ----------
__global__ void k_sumslab(const float* __restrict__ slab, const Meta* __restrict__ meta,
                          float* __restrict__ rowsum) {
  const int idx = blockIdx.x * 256 + threadIdx.x;   // 320 blocks: idx in [0, NCLS*NROWS)
  const int c = idx >> 13;                           // idx / NROWS
  float s = 0.f;
#pragma unroll
  for (int sp = 0; sp < CS; ++sp) s += slab[(size_t)sp * NCLS * NROWS + idx];
  rowsum[idx] = s - (float)meta->padc[c];            // pads contributed exp2(0)=1 each
}

// ---------- kernel 6: per-row loss + partials + last-block final reduce ----------
__global__ void k_fin(const float* __restrict__ rowsum, const float* __restrict__ diag,
                      const int* __restrict__ cls, const Meta* __restrict__ meta,
                      float* __restrict__ partials, int* __restrict__ counter,
                      float* __restrict__ out) {
  __shared__ float red[256];
  const int tid = threadIdx.x;
  const int i = blockIdx.x * 256 + tid;   // 32 blocks x 256 thr
  const int ci = cls[i];
  const float self = diag[i];
  float L[NCLS];
  float mx = -1e30f;
#pragma unroll
  for (int c = 0; c < NCLS; ++c) {
    float sc = rowsum[c * NROWS + i] - ((c == ci) ? self : 0.f);
    float py = (float)meta->cnt[c] - ((c == ci) ? 1.f : 0.f);
    L[c] = __logf(sc) - __logf(py);
    mx = fmaxf(mx, L[c]);
  }
  float sum = 0.f, Lt = 0.f;
#pragma unroll
  for (int c = 0; c < NCLS; ++c) {
    sum += __expf(L[c] - mx);
    Lt += (c == ci) ? L[c] : 0.f;
  }
  const float lse = mx + __logf(sum);
  red[tid] = (i >= NCLS) ? (lse - Lt) : 0.f;
  __syncthreads();
  for (int st = 128; st > 0; st >>= 1) {
    if (tid < st) red[tid] += red[tid + st];
    __syncthreads();
  }
  if (tid == 0) {
    partials[blockIdx.x] = red[0];
    __threadfence();
    int old = atomicAdd(counter, 1);
    if (old == (int)gridDim.x - 1) {      // last block: deterministic fixed-order sum
      __threadfence();
      float t = 0.f;
      for (int b = 0; b < (int)gridDim.x; ++b) t += partials[b];
      out[0] = t / (float)(NROWS - NCLS);
    }
  }
}

extern "C" void kernel_launch(void* const* d_in, const int* in_sizes, int n_in,
                              void* d_out, int out_size, void* d_ws, size_t ws_size,
                              hipStream_t stream) {
  const float* label = (const float*)d_in[0];
  const float* feat  = (const float*)d_in[1];
  char* w = (char*)d_ws;
  __hip_bfloat16* featB = (__hip_bfloat16*)(w + OFF_FEATB);
  __hip_bfloat16* featA = (__hip_bfloat16*)(w + OFF_FEATA);
  float* slab    = (float*)(w + OFF_SLAB);
  float* rowsum  = (float*)(w + OFF_ROWSUM);
  float* diag    = (float*)(w + OFF_DIAG);
  int*   cls     = (int*)(w + OFF_CLS);
  int*   perm    = (int*)(w + OFF_PERM);
  int*   tileCls = (int*)(w + OFF_TILECLS);
  int*   histg   = (int*)(w + OFF_HISTG);
  Meta*  meta    = (Meta*)(w + OFF_META);
  float* part    = (float*)(w + OFF_PART);
  int*   counter = (int*)(w + OFF_CNT);

  k_clsB<<<NROWS * DIM / 4 / 256, 256, 0, stream>>>(label, feat, featB, diag, cls, histg, perm, counter);
  k_scatter<<<1, 1024, 0, stream>>>(cls, histg, perm, tileCls, meta);
  k_convA<<<MMAX * DIM / 4 / 256, 256, 0, stream>>>(feat, perm, featA);
  k_main<<<dim3(32, CS), 256, 0, stream>>>(featA, featB, tileCls, meta, slab);
  k_sumslab<<<NCLS * NROWS / 256, 256, 0, stream>>>(slab, meta, rowsum);
  k_fin<<<NROWS / 256, 256, 0, stream>>>(rowsum, diag, cls, meta, part, counter, (float*)d_out);
}

// Round 6
// 47.224 us; speedup vs baseline: 1.9741x; 1.1348x over previous
//
#include <hip/hip_runtime.h>
#include <hip/hip_bf16.h>

// softConLoss: loss = -mean_{i>=10} log_softmax_c( log(s_c(i)/py_c(i)) )[cls_i]
//   s_c(i) = sum_{j != i, cls_j == c} exp(feat_i . feat_j / 0.1)
// R6: no column permutation. s = exp(G) @ label done as QK-MFMA -> exp2 ->
// in-register bf16 pack + permlane32_swap -> PV-MFMA vs one-hot tile (T12).
// 3-kernel chain: prep -> main -> fin.

constexpr int NROWS = 8192;
constexpr int DIM   = 128;
constexpr int NCLS  = 10;
constexpr int CS    = 16;       // j-splits (grid.y of k_main)
constexpr int NT    = NROWS / 32;  // 256 j-tiles
constexpr float SCALEF = 14.4269504089f; // (1/TEMP) * log2(e)

typedef __attribute__((ext_vector_type(8)))  short  short8;
typedef __attribute__((ext_vector_type(16))) float  f32x16;
typedef unsigned int uint;

// ---- workspace layout (bytes), ~9.9 MB ----
constexpr size_t OFF_FEATU = 0;                                    // bf16 [NROWS][DIM]
constexpr size_t OFF_FEATB = OFF_FEATU + (size_t)NROWS * DIM * 2;  // bf16 [NROWS][DIM] * SCALEF
constexpr size_t OFF_LBFT  = OFF_FEATB + (size_t)NROWS * DIM * 2;  // bf16 [NT][2 jh][2 hi][32 c][8]
constexpr size_t OFF_SLAB  = OFF_LBFT + (size_t)NT * 128 * 16;     // f32 [CS][NCLS][NROWS]
constexpr size_t OFF_DIAG  = OFF_SLAB + (size_t)CS * NCLS * NROWS * 4; // f32 [NROWS]
constexpr size_t OFF_CLS   = OFF_DIAG + (size_t)NROWS * 4;         // int [NROWS]
constexpr size_t OFF_HISTG = OFF_CLS + (size_t)NROWS * 4;          // int [128][NCLS]
constexpr size_t OFF_PART  = OFF_HISTG + (size_t)128 * NCLS * 4;   // f32 [64]
constexpr size_t OFF_CNT   = OFF_PART + 256;                       // int

__device__ inline float exp2a(float x) {
#if __has_builtin(__builtin_amdgcn_exp2f)
  return __builtin_amdgcn_exp2f(x);
#else
  return exp2f(x);
#endif
}

__device__ inline uint pkbf(float a, float b) {  // pack 2 f32 -> dword of 2 bf16
  __hip_bfloat16 ha = __float2bfloat16(a), hb = __float2bfloat16(b);
  return (uint)(*(unsigned short*)&ha) | ((uint)(*(unsigned short*)&hb) << 16);
}

// ---------- kernel 1: conversions + diag + cls + chunk hists + one-hot tiles ----------
// 256 blocks x 256 thr. Blocks 0-31 also do cls/hist; blocks 128-255 build LbfT.
__global__ void k_prep(const float* __restrict__ label, const float* __restrict__ feat,
                       __hip_bfloat16* __restrict__ featU, __hip_bfloat16* __restrict__ featB,
                       short8* __restrict__ LbfT, float* __restrict__ diag,
                       int* __restrict__ cls, int* __restrict__ histg,
                       int* __restrict__ counter) {
  const int gid = blockIdx.x * 256 + threadIdx.x;
  const int lane = threadIdx.x & 63;
  {  // featU / featB / diag (32 consecutive threads own one row)
    int e = gid * 4;
    float4 v = *(const float4*)(feat + e);
    __hip_bfloat16 u0 = __float2bfloat16(v.x), u1 = __float2bfloat16(v.y);
    __hip_bfloat16 u2 = __float2bfloat16(v.z), u3 = __float2bfloat16(v.w);
    __hip_bfloat16 b0 = __float2bfloat16(v.x * SCALEF), b1 = __float2bfloat16(v.y * SCALEF);
    __hip_bfloat16 b2 = __float2bfloat16(v.z * SCALEF), b3 = __float2bfloat16(v.w * SCALEF);
    featU[e + 0] = u0; featU[e + 1] = u1; featU[e + 2] = u2; featU[e + 3] = u3;
    featB[e + 0] = b0; featB[e + 1] = b1; featB[e + 2] = b2; featB[e + 3] = b3;
    float sd = __bfloat162float(u0) * __bfloat162float(b0)
             + __bfloat162float(u1) * __bfloat162float(b1)
             + __bfloat162float(u2) * __bfloat162float(b2)
             + __bfloat162float(u3) * __bfloat162float(b3);
#pragma unroll
    for (int st = 1; st < 32; st <<= 1) sd += __shfl_xor(sd, st, 64);
    // store bf16-rounded: must match exactly what the PV-MFMA accumulated
    if ((gid & 31) == 0) diag[gid >> 5] = __bfloat162float(__float2bfloat16(exp2a(sd)));
  }
  if (gid == 0) *counter = 0;    // reset every call (graph replays)
  if (gid < NROWS) {             // class ids + per-64-row-chunk histograms
    int c = 0;
#pragma unroll
    for (int j = 0; j < NCLS; ++j) if (label[gid * NCLS + j] > 0.5f) c = j;
    cls[gid] = c;
    const int chunk = gid >> 6;
#pragma unroll
    for (int cc = 0; cc < NCLS; ++cc) {
      unsigned long long m = __ballot(c == cc);
      if (lane == cc) histg[chunk * NCLS + cc] = __popcll(m);
    }
  }
  if (gid >= 32768) {            // one-hot tiles: [t][jh][hi][c][idx8] bf16
    int w = gid - 32768;         // 32768 writers x 16B
    int t = w >> 7, widx = w & 127;
    int jh = widx >> 6, h2 = (widx >> 5) & 1, c = widx & 31;
    int jb = t * 32 + jh * 16 + h2 * 8;
    short8 out = {0, 0, 0, 0, 0, 0, 0, 0};
    if (c < NCLS) {
#pragma unroll
      for (int m = 0; m < 8; ++m)
        out[m] = (label[(jb + m) * NCLS + c] > 0.5f) ? (short)0x3F80 : (short)0;
    }
    LbfT[(size_t)t * 128 + widx] = out;
  }
}

// ---------- kernel 2: main — QK-MFMA -> exp2 -> PV-MFMA vs one-hot ----------
// 256 thr = 4 waves; wave owns 64 i-rows (2 strips of 32) sharing A-frags.
// grid (32 i-blocks, CS j-splits); 16 j-tiles per block, double-buffered LDS.
__device__ inline f32x16 pvstep(const f32x16& D, short8 lt0, short8 lt1, f32x16 O) {
  uint pk[8];
#pragma unroll
  for (int r = 0; r < 8; ++r) pk[r] = pkbf(exp2a(D[2 * r]), exp2a(D[2 * r + 1]));
  // permlane32_swap(a,b): a' = {a.lo, b.lo}, b' = {a.hi, b.hi}  -> frag dwords
  uint a0 = pk[0], b0 = pk[2];
  asm("v_permlane32_swap_b32 %0, %1" : "+v"(a0), "+v"(b0));
  uint a1 = pk[1], b1 = pk[3];
  asm("v_permlane32_swap_b32 %0, %1" : "+v"(a1), "+v"(b1));
  uint a2 = pk[4], b2 = pk[6];
  asm("v_permlane32_swap_b32 %0, %1" : "+v"(a2), "+v"(b2));
  uint a3 = pk[5], b3 = pk[7];
  asm("v_permlane32_swap_b32 %0, %1" : "+v"(a3), "+v"(b3));
  union { uint u[4]; short8 s; } f1, f2;
  f1.u[0] = a0; f1.u[1] = a1; f1.u[2] = b0; f1.u[3] = b1;   // P cols j0..15
  f2.u[0] = a2; f2.u[1] = a3; f2.u[2] = b2; f2.u[3] = b3;   // P cols j16..31
  O = __builtin_amdgcn_mfma_f32_32x32x16_bf16(f1.s, lt0, O, 0, 0, 0);
  O = __builtin_amdgcn_mfma_f32_32x32x16_bf16(f2.s, lt1, O, 0, 0, 0);
  return O;
}

__global__ __launch_bounds__(256, 2) void k_main(const __hip_bfloat16* __restrict__ featU,
                                                 const __hip_bfloat16* __restrict__ featB,
                                                 const short8* __restrict__ LbfT,
                                                 float* __restrict__ slab) {
  __shared__ __align__(16) char ldsA[2][8192];  // 32 j-rows x 256 B, XOR-swizzled
  __shared__ __align__(16) char ldsL[2][2048];  // [jh][hi][c][idx8] bf16, linear
  const int tid  = threadIdx.x;
  const int lane = tid & 63, wid = tid >> 6;
  const int il   = lane & 31, hi = lane >> 5;
  const int wbase = blockIdx.x * 256 + wid * 64;
  const int split = blockIdx.y;

  const short8* fb0 = (const short8*)(featB + (size_t)(wbase + il) * DIM);
  const short8* fb1 = (const short8*)(featB + (size_t)(wbase + 32 + il) * DIM);
  short8 bfrag0[8], bfrag1[8];
#pragma unroll
  for (int kk = 0; kk < 8; ++kk) { bfrag0[kk] = fb0[kk * 2 + hi]; bfrag1[kk] = fb1[kk * 2 + hi]; }

  f32x16 O0, O1;
#pragma unroll
  for (int r = 0; r < 16; ++r) { O0[r] = 0.f; O1[r] = 0.f; }

  // staging slots (A swizzle: byte col ^= (row&15)<<4; L linear)
  const int r0 = tid >> 4, s0 = tid & 15, r1 = r0 + 16;
  const int offA0 = r0 * 256 + ((s0 * 16) ^ ((r0 & 15) << 4));
  const int offA1 = r1 * 256 + ((s0 * 16) ^ ((r1 & 15) << 4));

  {
    const short8* sA = (const short8*)(featU + (size_t)split * 32 * DIM);
    *(short8*)(&ldsA[0][offA0]) = sA[r0 * 16 + s0];
    *(short8*)(&ldsA[0][offA1]) = sA[r1 * 16 + s0];
    if (tid < 128) *(short8*)(&ldsL[0][tid * 16]) = LbfT[(size_t)split * 128 + tid];
  }
  __syncthreads();

  int cur = 0;
  for (int t = split; t < NT; t += CS) {
    const int tn = t + CS;
    const bool pf = tn < NT;
    short8 vA0, vA1, vL;
    if (pf) {  // issue next-tile loads early; latency hides under MFMA+exp
      const short8* sA = (const short8*)(featU + (size_t)tn * 32 * DIM);
      vA0 = sA[r0 * 16 + s0];
      vA1 = sA[r1 * 16 + s0];
      if (tid < 128) vL = LbfT[(size_t)tn * 128 + tid];
    }

    f32x16 D0, D1;
#pragma unroll
    for (int r = 0; r < 16; ++r) { D0[r] = 0.f; D1[r] = 0.f; }
#pragma unroll
    for (int kk = 0; kk < 8; ++kk) {
      int off = il * 256 + (((kk * 32) + hi * 16) ^ ((il & 15) << 4));
      short8 a = *(const short8*)(&ldsA[cur][off]);   // A shared by both strips
      D0 = __builtin_amdgcn_mfma_f32_32x32x16_bf16(a, bfrag0[kk], D0, 0, 0, 0);
      D1 = __builtin_amdgcn_mfma_f32_32x32x16_bf16(a, bfrag1[kk], D1, 0, 0, 0);
    }

    // one-hot B-frags (shared by both strips): lane reads [jh][hi][c=il][8]
    short8 lt0 = *(const short8*)(&ldsL[cur][hi * 512 + il * 16]);
    short8 lt1 = *(const short8*)(&ldsL[cur][1024 + hi * 512 + il * 16]);

    O0 = pvstep(D0, lt0, lt1, O0);
    O1 = pvstep(D1, lt0, lt1, O1);

    if (pf) {
      *(short8*)(&ldsA[cur ^ 1][offA0]) = vA0;
      *(short8*)(&ldsA[cur ^ 1][offA1]) = vA1;
      if (tid < 128) *(short8*)(&ldsL[cur ^ 1][tid * 16]) = vL;
    }
    __syncthreads();
    cur ^= 1;
  }

  // O layout: col = lane&31 = class, row = (reg&3)+8*(reg>>2)+4*hi = i-offset
  if (il < NCLS) {
#pragma unroll
    for (int reg = 0; reg < 16; ++reg) {
      int ioff = (reg & 3) + 8 * (reg >> 2) + 4 * hi;
      slab[((size_t)split * NCLS + il) * NROWS + wbase + ioff] = O0[reg];
      slab[((size_t)split * NCLS + il) * NROWS + wbase + 32 + ioff] = O1[reg];
    }
  }
}

// ---------- kernel 3: slab reduce (wide) + per-row loss + final reduce ----------
// 64 blocks x 256 thr; block owns 128 rows. Phase 1: coalesced split-sums into
// LDS. Phase 2: per-row loss. Last block folds partials (deterministic order).
__global__ void k_fin(const float* __restrict__ slab, const float* __restrict__ diag,
                      const int* __restrict__ cls, const int* __restrict__ histg,
                      float* __restrict__ partials, int* __restrict__ counter,
                      float* __restrict__ out) {
  __shared__ float ssum[NCLS][128];
  __shared__ int hcnt[128][NCLS];
  __shared__ float red[128];
  const int tid = threadIdx.x;
  const int b = blockIdx.x;
  // class counts (redundant per block): reduce 128 chunk-hists
  if (tid < 128) {
#pragma unroll
    for (int c = 0; c < NCLS; ++c) hcnt[tid][c] = histg[tid * NCLS + c];
  }
  __syncthreads();
  for (int st = 64; st > 0; st >>= 1) {
    if (tid < st) {
#pragma unroll
      for (int c = 0; c < NCLS; ++c) hcnt[tid][c] += hcnt[tid + st][c];
    }
    __syncthreads();
  }
  // phase 1: sum slab over splits for this block's 128 rows x 10 classes
#pragma unroll
  for (int pp = 0; pp < 5; ++pp) {
    int p = tid + pp * 256;            // p in [0,1280): c = p>>7, ii = p&127
    int c = p >> 7, ii = p & 127;
    float s = 0.f;
#pragma unroll
    for (int sp = 0; sp < CS; ++sp)
      s += slab[((size_t)sp * NCLS + c) * NROWS + b * 128 + ii];
    ssum[c][ii] = s;
  }
  __syncthreads();
  // phase 2: per-row loss
  if (tid < 128) {
    const int i = b * 128 + tid;
    const int ci = cls[i];
    const float self = diag[i];
    float L[NCLS];
    float mx = -1e30f;
#pragma unroll
    for (int c = 0; c < NCLS; ++c) {
      float sc = ssum[c][tid] - ((c == ci) ? self : 0.f);
      float py = (float)hcnt[0][c] - ((c == ci) ? 1.f : 0.f);
      L[c] = __logf(sc) - __logf(py);
      mx = fmaxf(mx, L[c]);
    }
    float sum = 0.f, Lt = 0.f;
#pragma unroll
    for (int c = 0; c < NCLS; ++c) {
      sum += __expf(L[c] - mx);
      Lt += (c == ci) ? L[c] : 0.f;
    }
    const float lse = mx + __logf(sum);
    red[tid] = (i >= NCLS) ? (lse - Lt) : 0.f;
  }
  __syncthreads();
  for (int st = 64; st > 0; st >>= 1) {
    if (tid < st) red[tid] += red[tid + st];
    __syncthreads();
  }
  if (tid == 0) {
    partials[b] = red[0];
    __threadfence();
    int old = atomicAdd(counter, 1);
    if (old == (int)gridDim.x - 1) {   // last block: deterministic fixed-order sum
      __threadfence();
      float t = 0.f;
      for (int bb = 0; bb < (int)gridDim.x; ++bb) t += partials[bb];
      out[0] = t / (float)(NROWS - NCLS);
    }
  }
}

extern "C" void kernel_launch(void* const* d_in, const int* in_sizes, int n_in,
                              void* d_out, int out_size, void* d_ws, size_t ws_size,
                              hipStream_t stream) {
  const float* label = (const float*)d_in[0];
  const float* feat  = (const float*)d_in[1];
  char* w = (char*)d_ws;
  __hip_bfloat16* featU = (__hip_bfloat16*)(w + OFF_FEATU);
  __hip_bfloat16* featB = (__hip_bfloat16*)(w + OFF_FEATB);
  short8* LbfT   = (short8*)(w + OFF_LBFT);
  float* slab    = (float*)(w + OFF_SLAB);
  float* diag    = (float*)(w + OFF_DIAG);
  int*   cls     = (int*)(w + OFF_CLS);
  int*   histg   = (int*)(w + OFF_HISTG);
  float* part    = (float*)(w + OFF_PART);
  int*   counter = (int*)(w + OFF_CNT);

  k_prep<<<256, 256, 0, stream>>>(label, feat, featU, featB, LbfT, diag, cls, histg, counter);
  k_main<<<dim3(32, CS), 256, 0, stream>>>(featU, featB, LbfT, slab);
  k_fin<<<64, 256, 0, stream>>>(slab, diag, cls, histg, part, counter, (float*)d_out);
}